// Round 5
// baseline (857.488 us; speedup 1.0000x reference)
//
#include <hip/hip_runtime.h>
#include <stdint.h>

#define NN    6000
#define KNNC  10
#define MM    (NN * 2 * (KNNC + 1))   // 132000
#define DD    (2 * NN)                // 12000
#define LCH   3                       // hidden layers (LC-1)
#define BLK   256                     // fill / scatter block size
#define MBLK  128                     // mlp block size (2 waves)

#define NV        ((long long)DD * DD / 4)   // 36,000,000 float4s
#define FILLGRID  2048
#define MLPGRID   ((MM + MBLK - 1) / MBLK)   // 1032
#define SCGRID    ((MM + BLK - 1) / BLK)     // 516

// Round-5: same three sequential kernels; the MLP's weight-load path is the
// target. R4 decomposition (R2 proved the ~375us harness re-poison fill is
// inside dur_us): standalone mlp ~= 250us vs a ~21us VALU floor, and it is
// SLOWER than R1's fused kernel where only 2 MLP waves/CU ran. The uniform
// weight loads (address independent of tid, const __restrict__) scalarize
// to s_load_dwordx4 -> each wave streams 48KB through the small K$ 3x, and
// 8 MLP waves/CU thrash it 4x harder than R1's 2 waves/CU (explains
// standalone > fused). Fix: launder the per-layer weight base pointer
// through an empty asm into a VGPR -> compiler must emit per-lane
// global_load_dwordx4; all lanes present the same address -> single L1
// transaction, broadcast; 16KB/layer is L1-resident and shared by all waves
// on the CU; fine-grained vmcnt pipelining instead of coarse lgkm drains.
// Also BLK 256->128 for the MLP: sH 64KB->32KB -> 5 blocks/CU = 10 waves/CU.

__global__ __launch_bounds__(BLK) void zero_fill(float* __restrict__ out) {
    // Pure streaming float4 stores, 0 LDS: clone of the 6.15 TB/s rocclr fill.
    const long long t0 = (long long)blockIdx.x * BLK + threadIdx.x;
    const long long stride = (long long)FILLGRID * BLK;
    float4 z = make_float4(0.f, 0.f, 0.f, 0.f);
    float4* outv = (float4*)out;
    for (long long i = t0; i < NV; i += stride) outv[i] = z;
}

__global__ __launch_bounds__(MBLK) void mlp(
    const float* __restrict__ CK,    // [MM,3]
    const float* __restrict__ Win,   // [3,64]
    const float* __restrict__ bin,   // [64]
    const float* __restrict__ Whid,  // [3,64,64]
    const float* __restrict__ bhid,  // [3,64]
    const float* __restrict__ Wout,  // [64,4]
    const float* __restrict__ bout,  // [4]
    float* __restrict__ vals)        // [MM,2] (workspace)
{
    __shared__ float sH[64 * MBLK];  // activations [k][tid], 32 KiB

    const int tid = threadIdx.x;
    const int m0  = blockIdx.x * MBLK + tid;   // 0..132095
    const int m   = m0 < MM ? m0 : MM - 1;     // clamp loads, guard store

    const float x0 = CK[m * 3 + 0];
    const float x1 = CK[m * 3 + 1];
    const float x2 = CK[m * 3 + 2];

    float* __restrict__ hcol = sH + tid;       // h[k] lives at hcol[k*MBLK]

    // Input layer 3 -> 64; small uniform weights (s_load is fine here: 1KB).
#pragma unroll
    for (int j = 0; j < 64; j++) {
        float a = bin[j];
        a = fmaf(x0, Win[j],       a);
        a = fmaf(x1, Win[64 + j],  a);
        a = fmaf(x2, Win[128 + j], a);
        hcol[j * MBLK] = fmaxf(a, 0.0f);       // static addr: ds_write_b32
    }

    // Hidden layers: g_j = sum_k W[k][j] * h_k (row-major W matches h @ W).
#pragma unroll 1
    for (int l = 0; l < LCH; l++) {
        // Launder the weight base pointer into a VGPR: defeats uniformity
        // analysis so loads are per-lane global_load_dwordx4 (same addr on
        // all lanes -> one L1 transaction, broadcast), NOT s_load via the
        // thrashed scalar cache.
        uintptr_t wp = (uintptr_t)(Whid + (l << 12));
        asm volatile("" : "+v"(wp));
        const float4* __restrict__ W4 = (const float4*)wp;

        const float* __restrict__ bh = bhid + (l << 6);
        float g[64];
#pragma unroll
        for (int j = 0; j < 64; j++) g[j] = bh[j];
#pragma unroll 8
        for (int k = 0; k < 64; k++) {
            const float hk = hcol[k * MBLK];   // ds_read_b32 (2-way alias: free)
            const float4* __restrict__ Wk = W4 + (k << 4);   // row k: 16 float4s
#pragma unroll
            for (int j4 = 0; j4 < 16; j4++) {
                float4 w = Wk[j4];             // vector load, L1 broadcast hit
                g[j4 * 4 + 0] = fmaf(w.x, hk, g[j4 * 4 + 0]);
                g[j4 * 4 + 1] = fmaf(w.y, hk, g[j4 * 4 + 1]);
                g[j4 * 4 + 2] = fmaf(w.z, hk, g[j4 * 4 + 2]);
                g[j4 * 4 + 3] = fmaf(w.w, hk, g[j4 * 4 + 3]);
            }
        }
#pragma unroll
        for (int j = 0; j < 64; j++) hcol[j * MBLK] = fmaxf(g[j], 0.0f);
    }

    // Output layer collapsed over mi: vals[:,mj] = C[:,mj] + C[:,mj+2]
    float v0 = bout[0] + bout[2];
    float v1 = bout[1] + bout[3];
#pragma unroll 8
    for (int k = 0; k < 64; k++) {
        float4 wo = *((const float4*)Wout + k);
        const float hk = hcol[k * MBLK];
        v0 = fmaf(hk, wo.x + wo.z, v0);
        v1 = fmaf(hk, wo.y + wo.w, v1);
    }
    if (m0 < MM) *(float2*)(vals + 2 * m0) = make_float2(v0, v1);
}

__global__ __launch_bounds__(BLK) void scatter_add(
    const float* __restrict__ vals,   // [MM,2]
    const int* __restrict__ coo,      // [2,MM]
    float* __restrict__ out)          // [DD*DD]
{
    const int t = blockIdx.x * BLK + threadIdx.x;
    if (t >= MM) return;
    const int r2 = coo[t] * 2;        // row index * MODES
    const int c2 = coo[MM + t] * 2;   // col index * MODES
    const float2 v = *(const float2*)(vals + 2 * t);
    // mj=0: element (r2, c2); mj=1: element (r2+1, c2+1) = +DD+1 flat
    const long long f0 = (long long)r2 * DD + c2;
    // Native global_atomic_add_f32 (fire-and-forget), not a CAS retry loop.
    unsafeAtomicAdd(out + f0, v.x);
    unsafeAtomicAdd(out + f0 + DD + 1, v.y);
}

extern "C" void kernel_launch(void* const* d_in, const int* in_sizes, int n_in,
                              void* d_out, int out_size, void* d_ws, size_t ws_size,
                              hipStream_t stream) {
    const float* CK   = (const float*)d_in[0];
    const float* Win  = (const float*)d_in[1];
    const float* bin  = (const float*)d_in[2];
    const float* Whid = (const float*)d_in[3];
    const float* bhid = (const float*)d_in[4];
    const float* Wout = (const float*)d_in[5];
    const float* bout = (const float*)d_in[6];
    const int* coo    = (const int*)d_in[7];
    float* out        = (float*)d_out;
    float* vals       = (float*)d_ws;

    mlp<<<MLPGRID, MBLK, 0, stream>>>(CK, Win, bin, Whid, bhid, Wout, bout, vals);
    zero_fill<<<FILLGRID, BLK, 0, stream>>>(out);
    scatter_add<<<SCGRID, BLK, 0, stream>>>(vals, coo, out);
}

// Round 6
// 699.278 us; speedup vs baseline: 1.2262x; 1.2262x over previous
//
#include <hip/hip_runtime.h>
#include <stdint.h>

#define NN    6000
#define KNNC  10
#define MM    (NN * 2 * (KNNC + 1))   // 132000
#define DD    (2 * NN)                // 12000
#define LCH   3                       // hidden layers (LC-1)
#define BLK   256

#define NV        ((long long)DD * DD / 4)   // 36,000,000 float4s
#define FILLGRID  2048
#define RB        256                  // rows per MLP block
#define RPL       4                    // rows per lane (RB/64)
#define MLPGRID   ((MM + RB - 1) / RB) // 516
#define SCGRID    ((MM + BLK - 1) / BLK)

// Round-6 MLP restructure. R4 (s_load weights, ~250us) and R5 (laundered
// vector loads, ~360us) proved the bottleneck is NOT which cache path the
// weights take: the old loop had arithmetic intensity 1 (64 weight floats
// per 64 FMA wave-instrs per k-step) and a desynchronized 48KB/wave weight
// stream that thrashes K$ (16KB) and L1 (32KB) alike, with stalls ADDING
// across waves. Fix = kill the per-wave weight stream:
//  - j-split: wave w computes channels [16w,16w+16) for ALL 256 block rows
//    -> each wave reads 1/4 of W per layer (4 uniform ds_read_b128 per k).
//  - W staged in LDS one layer at a time (16KB), __syncthreads lockstep ->
//    no desynchronized working set, weights read via broadcast DS pipe
//    (in-order, fine-grained lgkmcnt; no scalar-miss serialization).
//  - 4 rows/lane: g[4][16]=64 statically-indexed acc VGPRs; per k-step =
//    4 b128 + 4 b32 + 64 FMAs -> 4x arithmetic intensity.
// LDS 16KB W + 64KB sH[k][row] = 80KB -> 2 blocks/CU (8 waves). Per-CU
// budget: FMA 49k cyc (20.5us floor), DS 76-119k cyc -> mlp ~40-60us.
__global__ __launch_bounds__(BLK) void zero_fill(float* __restrict__ out) {
    // Pure streaming float4 stores, 0 LDS: clone of the 6.15 TB/s rocclr fill.
    const long long t0 = (long long)blockIdx.x * BLK + threadIdx.x;
    const long long stride = (long long)FILLGRID * BLK;
    float4 z = make_float4(0.f, 0.f, 0.f, 0.f);
    float4* outv = (float4*)out;
    for (long long i = t0; i < NV; i += stride) outv[i] = z;
}

__global__ __launch_bounds__(BLK, 2) void mlp(
    const float* __restrict__ CK,    // [MM,3]
    const float* __restrict__ Win,   // [3,64]
    const float* __restrict__ bin,   // [64]
    const float* __restrict__ Whid,  // [3,64,64]
    const float* __restrict__ bhid,  // [3,64]
    const float* __restrict__ Wout,  // [64,4]
    const float* __restrict__ bout,  // [4]
    float* __restrict__ vals)        // [MM,2] (workspace)
{
    __shared__ float sW[64 * 64];    // one layer's weights, 16 KiB
    __shared__ float sH[64 * RB];    // activations [k][row], 64 KiB

    const int tid   = threadIdx.x;
    const int wave  = tid >> 6;
    const int lane  = tid & 63;
    const int jo    = wave << 4;               // this wave's 16-channel slice
    const int rbase = blockIdx.x * RB;

    // Lane's 4 rows of inputs (clamped; stores guarded at the end).
    float x0[RPL], x1[RPL], x2[RPL];
#pragma unroll
    for (int r = 0; r < RPL; r++) {
        int m = rbase + r * 64 + lane;
        m = m < MM ? m : MM - 1;
        x0[r] = CK[m * 3 + 0];
        x1[r] = CK[m * 3 + 1];
        x2[r] = CK[m * 3 + 2];
    }

    // Input layer: this wave's 16 channels for its lanes' 4 rows.
    // (all waves together cover all 64 channels x 256 rows)
#pragma unroll
    for (int jj = 0; jj < 16; jj++) {
        const int j = jo + jj;
        const float w0 = Win[j], w1 = Win[64 + j], w2 = Win[128 + j];
        const float bj = bin[j];
#pragma unroll
        for (int r = 0; r < RPL; r++) {
            float a = fmaf(x2[r], w2, fmaf(x1[r], w1, fmaf(x0[r], w0, bj)));
            sH[j * RB + r * 64 + lane] = fmaxf(a, 0.f);   // lanes 4B apart: free
        }
    }
    __syncthreads();

    // Hidden layers, layer-lockstep.
#pragma unroll 1
    for (int l = 0; l < LCH; l++) {
        // Stage W_l: 1024 float4s, 4 per thread, coalesced from L2.
        {
            const float4* __restrict__ Wg = (const float4*)(Whid + (l << 12));
            float4* __restrict__ sW4 = (float4*)sW;
#pragma unroll
            for (int i = 0; i < 4; i++) sW4[i * 256 + tid] = Wg[i * 256 + tid];
        }
        __syncthreads();

        float g[RPL][16];
#pragma unroll
        for (int jj = 0; jj < 16; jj++) {
            const float bj = bhid[(l << 6) + jo + jj];
#pragma unroll
            for (int r = 0; r < RPL; r++) g[r][jj] = bj;
        }

#pragma unroll 4
        for (int k = 0; k < 64; k++) {
            // wave-uniform broadcast reads of this wave's 16-channel slice
            const float4 wa = *(const float4*)(sW + (k << 6) + jo);
            const float4 wb = *(const float4*)(sW + (k << 6) + jo + 4);
            const float4 wc = *(const float4*)(sW + (k << 6) + jo + 8);
            const float4 wd = *(const float4*)(sW + (k << 6) + jo + 12);
            float hk[RPL];
#pragma unroll
            for (int r = 0; r < RPL; r++) hk[r] = sH[k * RB + r * 64 + lane];
#pragma unroll
            for (int r = 0; r < RPL; r++) {
                g[r][0]  = fmaf(wa.x, hk[r], g[r][0]);
                g[r][1]  = fmaf(wa.y, hk[r], g[r][1]);
                g[r][2]  = fmaf(wa.z, hk[r], g[r][2]);
                g[r][3]  = fmaf(wa.w, hk[r], g[r][3]);
                g[r][4]  = fmaf(wb.x, hk[r], g[r][4]);
                g[r][5]  = fmaf(wb.y, hk[r], g[r][5]);
                g[r][6]  = fmaf(wb.z, hk[r], g[r][6]);
                g[r][7]  = fmaf(wb.w, hk[r], g[r][7]);
                g[r][8]  = fmaf(wc.x, hk[r], g[r][8]);
                g[r][9]  = fmaf(wc.y, hk[r], g[r][9]);
                g[r][10] = fmaf(wc.z, hk[r], g[r][10]);
                g[r][11] = fmaf(wc.w, hk[r], g[r][11]);
                g[r][12] = fmaf(wd.x, hk[r], g[r][12]);
                g[r][13] = fmaf(wd.y, hk[r], g[r][13]);
                g[r][14] = fmaf(wd.z, hk[r], g[r][14]);
                g[r][15] = fmaf(wd.w, hk[r], g[r][15]);
            }
        }
        __syncthreads();   // all reads of sH/sW for layer l complete

        // h = relu(g): write this wave's 16 channels for its 4x64 rows.
#pragma unroll
        for (int jj = 0; jj < 16; jj++) {
#pragma unroll
            for (int r = 0; r < RPL; r++)
                sH[(jo + jj) * RB + r * 64 + lane] = fmaxf(g[r][jj], 0.f);
        }
        __syncthreads();   // h ready for next layer / output
    }

    // Output layer collapsed over mi: vals[:,mj] = C[:,mj] + C[:,mj+2]
    float v0[RPL], v1[RPL];
    const float b02 = bout[0] + bout[2], b13 = bout[1] + bout[3];
#pragma unroll
    for (int r = 0; r < RPL; r++) { v0[r] = b02; v1[r] = b13; }
#pragma unroll 8
    for (int k = 0; k < 64; k++) {
        const float4 wo = ((const float4*)Wout)[k];
        const float wxz = wo.x + wo.z, wyw = wo.y + wo.w;
#pragma unroll
        for (int r = 0; r < RPL; r++) {
            const float hk = sH[k * RB + r * 64 + lane];
            v0[r] = fmaf(hk, wxz, v0[r]);
            v1[r] = fmaf(hk, wyw, v1[r]);
        }
    }
#pragma unroll
    for (int r = 0; r < RPL; r++) {
        const int m = rbase + r * 64 + lane;
        if (m < MM) *(float2*)(vals + 2 * m) = make_float2(v0[r], v1[r]);
    }
}

__global__ __launch_bounds__(BLK) void scatter_add(
    const float* __restrict__ vals,   // [MM,2]
    const int* __restrict__ coo,      // [2,MM]
    float* __restrict__ out)          // [DD*DD]
{
    const int t = blockIdx.x * BLK + threadIdx.x;
    if (t >= MM) return;
    const int r2 = coo[t] * 2;        // row index * MODES
    const int c2 = coo[MM + t] * 2;   // col index * MODES
    const float2 v = *(const float2*)(vals + 2 * t);
    // mj=0: element (r2, c2); mj=1: element (r2+1, c2+1) = +DD+1 flat
    const long long f0 = (long long)r2 * DD + c2;
    // Native global_atomic_add_f32 (fire-and-forget), not a CAS retry loop.
    unsafeAtomicAdd(out + f0, v.x);
    unsafeAtomicAdd(out + f0 + DD + 1, v.y);
}

extern "C" void kernel_launch(void* const* d_in, const int* in_sizes, int n_in,
                              void* d_out, int out_size, void* d_ws, size_t ws_size,
                              hipStream_t stream) {
    const float* CK   = (const float*)d_in[0];
    const float* Win  = (const float*)d_in[1];
    const float* bin  = (const float*)d_in[2];
    const float* Whid = (const float*)d_in[3];
    const float* bhid = (const float*)d_in[4];
    const float* Wout = (const float*)d_in[5];
    const float* bout = (const float*)d_in[6];
    const int* coo    = (const int*)d_in[7];
    float* out        = (float*)d_out;
    float* vals       = (float*)d_ws;

    mlp<<<MLPGRID, BLK, 0, stream>>>(CK, Win, bin, Whid, bhid, Wout, bout, vals);
    zero_fill<<<FILLGRID, BLK, 0, stream>>>(out);
    scatter_add<<<SCGRID, BLK, 0, stream>>>(vals, coo, out);
}

// Round 8
// 662.368 us; speedup vs baseline: 1.2946x; 1.0557x over previous
//
#include <hip/hip_runtime.h>
#include <stdint.h>

#define NN    6000
#define KNNC  10
#define MM    (NN * 2 * (KNNC + 1))   // 132000
#define DD    (2 * NN)                // 12000
#define LCH   3                       // hidden layers (LC-1)
#define BLK   256

#define RB        256                  // rows per MLP block
#define RPL       4                    // rows per lane (RB/64)
#define MLPGRID   ((MM + RB - 1) / RB) // 516
#define OUTBYTES  ((size_t)DD * DD * 4)   // 576,000,000

// Round-8 = Round-7 with the scatter-duplication bug fixed. R7 failed
// correctness (absmax 0.27 ~= 3x a typical |value|): all four waves compute
// identical v0/v1 for the SAME 256 rows (slot lane*4+r is wave-independent;
// in R6 the redundant waves stored the same value idempotently to vals[m]),
// and the fused scatter turned that into a 4x atomicAdd. Fix: wave w
// scatters only element r==w of its lane's group (each row scattered exactly
// once; value picked by a static ?: chain - no dynamic register indexing).
// Kept from R7: (1) zero-fill via hipMemsetAsync (the rocclr fill path that
// sustains 6.15 TB/s on this exact buffer -> known ~94us constant);
// (2) scatter fused into the MLP epilogue (kills a launch + vals round-trip);
// (3) packed rows lane*4+r: activations move as b128 (5 b128/k-step,
// 16-b128 relu writeback), CK inputs as 3 aligned float4/lane.
__global__ __launch_bounds__(BLK, 2) void mlp_scatter(
    const float* __restrict__ CK,    // [MM,3]
    const float* __restrict__ Win,   // [3,64]
    const float* __restrict__ bin,   // [64]
    const float* __restrict__ Whid,  // [3,64,64]
    const float* __restrict__ bhid,  // [3,64]
    const float* __restrict__ Wout,  // [64,4]
    const float* __restrict__ bout,  // [4]
    const int* __restrict__ coo,     // [2,MM]
    float* __restrict__ out)         // [DD*DD], pre-zeroed by memset
{
    __shared__ float sW[64 * 64];    // one layer's weights, 16 KiB
    __shared__ float sH[64 * RB];    // activations [k][row], row=lane*4+r, 64 KiB

    const int tid   = threadIdx.x;
    const int wave  = tid >> 6;
    const int lane  = tid & 63;
    const int jo    = wave << 4;               // this wave's 16-channel slice
    const int rbase = blockIdx.x * RB;
    const int mb0   = rbase + lane * 4;        // lane's first row (mult of 4)
    const int mb    = mb0 < MM ? mb0 : MM - 4; // MM%4==0: groups all-in or all-out

    // Lane's 4 rows of inputs: 12 consecutive floats, 48B-aligned -> 3 float4.
    const float4 f0 = *(const float4*)(CK + mb * 3);
    const float4 f1 = *(const float4*)(CK + mb * 3 + 4);
    const float4 f2 = *(const float4*)(CK + mb * 3 + 8);
    const float x0[RPL] = {f0.x, f0.w, f1.z, f2.y};
    const float x1[RPL] = {f0.y, f1.x, f1.w, f2.z};
    const float x2[RPL] = {f0.z, f1.y, f2.x, f2.w};

    // Input layer: this wave's 16 channels for its 4 packed rows.
#pragma unroll
    for (int jj = 0; jj < 16; jj++) {
        const int j = jo + jj;
        const float w0 = Win[j], w1 = Win[64 + j], w2 = Win[128 + j];
        const float bj = bin[j];
        float4 hv;
        hv.x = fmaxf(fmaf(x2[0], w2, fmaf(x1[0], w1, fmaf(x0[0], w0, bj))), 0.f);
        hv.y = fmaxf(fmaf(x2[1], w2, fmaf(x1[1], w1, fmaf(x0[1], w0, bj))), 0.f);
        hv.z = fmaxf(fmaf(x2[2], w2, fmaf(x1[2], w1, fmaf(x0[2], w0, bj))), 0.f);
        hv.w = fmaxf(fmaf(x2[3], w2, fmaf(x1[3], w1, fmaf(x0[3], w0, bj))), 0.f);
        *(float4*)(sH + j * RB + lane * 4) = hv;   // one b128 per channel
    }
    __syncthreads();

    // Hidden layers, layer-lockstep.
#pragma unroll 1
    for (int l = 0; l < LCH; l++) {
        {   // Stage W_l: 1024 float4s, 4 per thread, coalesced (L2-hot).
            const float4* __restrict__ Wg = (const float4*)(Whid + (l << 12));
            float4* __restrict__ sW4 = (float4*)sW;
#pragma unroll
            for (int i = 0; i < 4; i++) sW4[i * 256 + tid] = Wg[i * 256 + tid];
        }
        __syncthreads();

        float g[RPL][16];
#pragma unroll
        for (int jj = 0; jj < 16; jj++) {
            const float bj = bhid[(l << 6) + jo + jj];
#pragma unroll
            for (int r = 0; r < RPL; r++) g[r][jj] = bj;
        }

#pragma unroll 4
        for (int k = 0; k < 64; k++) {
            // 4 wave-uniform broadcast b128: this wave's 16-channel W slice.
            const float4 wa = *(const float4*)(sW + (k << 6) + jo);
            const float4 wb = *(const float4*)(sW + (k << 6) + jo + 4);
            const float4 wc = *(const float4*)(sW + (k << 6) + jo + 8);
            const float4 wd = *(const float4*)(sW + (k << 6) + jo + 12);
            // 1 b128: lane's 4 packed rows of h_k.
            const float4 hv = *(const float4*)(sH + k * RB + lane * 4);
            const float hk[RPL] = {hv.x, hv.y, hv.z, hv.w};
#pragma unroll
            for (int r = 0; r < RPL; r++) {
                g[r][0]  = fmaf(wa.x, hk[r], g[r][0]);
                g[r][1]  = fmaf(wa.y, hk[r], g[r][1]);
                g[r][2]  = fmaf(wa.z, hk[r], g[r][2]);
                g[r][3]  = fmaf(wa.w, hk[r], g[r][3]);
                g[r][4]  = fmaf(wb.x, hk[r], g[r][4]);
                g[r][5]  = fmaf(wb.y, hk[r], g[r][5]);
                g[r][6]  = fmaf(wb.z, hk[r], g[r][6]);
                g[r][7]  = fmaf(wb.w, hk[r], g[r][7]);
                g[r][8]  = fmaf(wc.x, hk[r], g[r][8]);
                g[r][9]  = fmaf(wc.y, hk[r], g[r][9]);
                g[r][10] = fmaf(wc.z, hk[r], g[r][10]);
                g[r][11] = fmaf(wc.w, hk[r], g[r][11]);
                g[r][12] = fmaf(wd.x, hk[r], g[r][12]);
                g[r][13] = fmaf(wd.y, hk[r], g[r][13]);
                g[r][14] = fmaf(wd.z, hk[r], g[r][14]);
                g[r][15] = fmaf(wd.w, hk[r], g[r][15]);
            }
        }
        __syncthreads();   // all reads of sW/sH for layer l complete

        // relu + writeback: 16 b128 (4 packed rows per channel).
#pragma unroll
        for (int jj = 0; jj < 16; jj++) {
            float4 hv;
            hv.x = fmaxf(g[0][jj], 0.f);
            hv.y = fmaxf(g[1][jj], 0.f);
            hv.z = fmaxf(g[2][jj], 0.f);
            hv.w = fmaxf(g[3][jj], 0.f);
            *(float4*)(sH + (jo + jj) * RB + lane * 4) = hv;
        }
        __syncthreads();   // h ready for next layer / output
    }

    // Output layer collapsed over mi: v[:,mj] = C[:,mj] + C[:,mj+2]
    float v0[RPL], v1[RPL];
    const float b02 = bout[0] + bout[2], b13 = bout[1] + bout[3];
#pragma unroll
    for (int r = 0; r < RPL; r++) { v0[r] = b02; v1[r] = b13; }
#pragma unroll 8
    for (int k = 0; k < 64; k++) {
        const float4 wo = ((const float4*)Wout)[k];
        const float wxz = wo.x + wo.z, wyw = wo.y + wo.w;
        const float4 hv = *(const float4*)(sH + k * RB + lane * 4);
        v0[0] = fmaf(hv.x, wxz, v0[0]);  v1[0] = fmaf(hv.x, wyw, v1[0]);
        v0[1] = fmaf(hv.y, wxz, v0[1]);  v1[1] = fmaf(hv.y, wyw, v1[1]);
        v0[2] = fmaf(hv.z, wxz, v0[2]);  v1[2] = fmaf(hv.z, wyw, v1[2]);
        v0[3] = fmaf(hv.w, wxz, v0[3]);  v1[3] = fmaf(hv.w, wyw, v1[3]);
    }

    // Fused scatter, DEDUPLICATED: all 4 waves hold identical v0/v1 for the
    // same rows, so wave w scatters only element r==w of its lane's 4-row
    // group -> each of the block's 256 rows is scattered exactly once.
    // Static ?: selects (no dynamic register-array indexing -> no scratch).
    if (mb0 < MM) {
        const int mrow = mb0 + wave;
        const float sv0 = wave == 0 ? v0[0] : wave == 1 ? v0[1]
                        : wave == 2 ? v0[2] : v0[3];
        const float sv1 = wave == 0 ? v1[0] : wave == 1 ? v1[1]
                        : wave == 2 ? v1[2] : v1[3];
        const int r2 = coo[mrow] * 2;        // row index * MODES
        const int c2 = coo[MM + mrow] * 2;   // col index * MODES
        const long long f0i = (long long)r2 * DD + c2;
        unsafeAtomicAdd(out + f0i, sv0);            // (2i, 2j)
        unsafeAtomicAdd(out + f0i + DD + 1, sv1);   // (2i+1, 2j+1)
    }
}

extern "C" void kernel_launch(void* const* d_in, const int* in_sizes, int n_in,
                              void* d_out, int out_size, void* d_ws, size_t ws_size,
                              hipStream_t stream) {
    const float* CK   = (const float*)d_in[0];
    const float* Win  = (const float*)d_in[1];
    const float* bin  = (const float*)d_in[2];
    const float* Whid = (const float*)d_in[3];
    const float* bhid = (const float*)d_in[4];
    const float* Wout = (const float*)d_in[5];
    const float* bout = (const float*)d_in[6];
    const int* coo    = (const int*)d_in[7];
    float* out        = (float*)d_out;

    // Zero the 576MB output on the rocclr fill path (proven 6.15 TB/s on
    // this buffer); stream-ordered ahead of the fused MLP+scatter.
    hipMemsetAsync(out, 0, OUTBYTES, stream);
    mlp_scatter<<<MLPGRID, BLK, 0, stream>>>(
        CK, Win, bin, Whid, bhid, Wout, bout, coo, out);
}

// Round 9
// 649.000 us; speedup vs baseline: 1.3212x; 1.0206x over previous
//
#include <hip/hip_runtime.h>
#include <stdint.h>

#define NN    6000
#define KNNC  10
#define MM    (NN * 2 * (KNNC + 1))   // 132000
#define DD    (2 * NN)                // 12000
#define LCH   3                       // hidden layers (LC-1)
#define BLK   256

#define RB        128                  // rows per MLP block
#define RPL       2                    // rows per lane (RB/64)
#define MLPGRID   ((MM + RB - 1) / RB) // 1032
#define OUTBYTES  ((size_t)DD * DD * 4)   // 576,000,000

// Round-9: occupancy + weight-path restructure of the proven R8 dataflow.
// R8 decomposition left mlp_scatter ~190us vs a 21us FMA floor, invariant
// across weight schemes. Two structural losses identified:
//  (1) grid quantization: 516 blocks at 2/CU (80KB LDS) = 512 slots -> 4 CUs
//      run a 3rd block serially -> ~1.5x makespan;
//  (2) 8 waves/CU can't hide the k-loop's LDS-latency chains (R2's direct
//      profile: VALUBusy 8% = stall-bound; stalls ADD across waves R4/R5).
// Fix: RB=128 (2 rows/lane), NO sW (weights via wave-uniform s_load: in a
// barrier-lockstep block all waves sit on the same 16KB layer -> K$-resident;
// R4's s_load failure was desynchronized waves streaming 48KB through the
// 16KB K$). Per k-step per wave: 1 s_load_dwordx16 (64B, this wave's 16
// channels) + 1 ds_read_b64 + 32 FMAs - weights cost zero VALU/DS slots.
// LDS = 32KB sH only -> 5 blocks/CU = 20 waves/CU; grid 1032 <= 1280 slots
// -> ALL blocks co-resident, zero tail. jo is readfirstlane'd so the
// compiler provably sees uniform addresses (else R5's per-lane-load trap).
__global__ __launch_bounds__(BLK, 4) void mlp_scatter(
    const float* __restrict__ CK,    // [MM,3]
    const float* __restrict__ Win,   // [3,64]
    const float* __restrict__ bin,   // [64]
    const float* __restrict__ Whid,  // [3,64,64]
    const float* __restrict__ bhid,  // [3,64]
    const float* __restrict__ Wout,  // [64,4]
    const float* __restrict__ bout,  // [4]
    const int* __restrict__ coo,     // [2,MM]
    float* __restrict__ out)         // [DD*DD], pre-zeroed by memset
{
    __shared__ float sH[64 * RB];    // activations [k][row], row=lane*2+r, 32 KiB

    const int tid  = threadIdx.x;
    const int wave = tid >> 6;
    const int lane = tid & 63;
    // Wave-uniform channel offset, forced into an SGPR so weight/bias loads
    // provably scalarize (s_load) instead of falling to per-lane vector loads.
    const int jo = __builtin_amdgcn_readfirstlane((tid >> 6) << 4);

    const int rbase = blockIdx.x * RB;
    const int mb0   = rbase + lane * 2;        // lane's first row (even)
    const int mb    = mb0 < MM ? mb0 : MM - 2; // MM even: clamp loads, guard stores

    // Lane's 2 rows of inputs: 6 consecutive floats, 8B-aligned -> 3 float2.
    const float2 ca = *(const float2*)(CK + mb * 3);      // x0r0 x1r0
    const float2 cb = *(const float2*)(CK + mb * 3 + 2);  // x2r0 x0r1
    const float2 cc = *(const float2*)(CK + mb * 3 + 4);  // x1r1 x2r1
    const float x0[RPL] = {ca.x, cb.y};
    const float x1[RPL] = {ca.y, cc.x};
    const float x2[RPL] = {cb.x, cc.y};

    // Input layer: this wave's 16 channels for its 2 packed rows.
#pragma unroll
    for (int jj = 0; jj < 16; jj++) {
        const int j = jo + jj;
        const float w0 = Win[j], w1 = Win[64 + j], w2 = Win[128 + j];  // s_load
        const float bj = bin[j];
        float2 hv;
        hv.x = fmaxf(fmaf(x2[0], w2, fmaf(x1[0], w1, fmaf(x0[0], w0, bj))), 0.f);
        hv.y = fmaxf(fmaf(x2[1], w2, fmaf(x1[1], w1, fmaf(x0[1], w0, bj))), 0.f);
        *(float2*)(sH + j * RB + lane * 2) = hv;
    }
    __syncthreads();

    // Hidden layers, barrier-lockstep (all waves on the same 16KB W -> K$-hot).
#pragma unroll 1
    for (int l = 0; l < LCH; l++) {
        const float* __restrict__ Wl = Whid + (l << 12) + jo;  // uniform SGPR base
        const float* __restrict__ bh = bhid + (l << 6) + jo;

        float g[RPL][16];
#pragma unroll
        for (int jj = 0; jj < 16; jj++) {
            const float bj = bh[jj];           // s_load
            g[0][jj] = bj;
            g[1][jj] = bj;
        }

#pragma unroll 4
        for (int k = 0; k < 64; k++) {
            // This wave's 16-channel weight slice: 64B uniform -> s_load_dwordx16.
            const float4 wa = *(const float4*)(Wl + (k << 6));
            const float4 wb = *(const float4*)(Wl + (k << 6) + 4);
            const float4 wc = *(const float4*)(Wl + (k << 6) + 8);
            const float4 wd = *(const float4*)(Wl + (k << 6) + 12);
            // Lane's 2 packed rows of h_k: one b64.
            const float2 hv = *(const float2*)(sH + k * RB + lane * 2);
            const float hk[RPL] = {hv.x, hv.y};
#pragma unroll
            for (int r = 0; r < RPL; r++) {
                g[r][0]  = fmaf(wa.x, hk[r], g[r][0]);
                g[r][1]  = fmaf(wa.y, hk[r], g[r][1]);
                g[r][2]  = fmaf(wa.z, hk[r], g[r][2]);
                g[r][3]  = fmaf(wa.w, hk[r], g[r][3]);
                g[r][4]  = fmaf(wb.x, hk[r], g[r][4]);
                g[r][5]  = fmaf(wb.y, hk[r], g[r][5]);
                g[r][6]  = fmaf(wb.z, hk[r], g[r][6]);
                g[r][7]  = fmaf(wb.w, hk[r], g[r][7]);
                g[r][8]  = fmaf(wc.x, hk[r], g[r][8]);
                g[r][9]  = fmaf(wc.y, hk[r], g[r][9]);
                g[r][10] = fmaf(wc.z, hk[r], g[r][10]);
                g[r][11] = fmaf(wc.w, hk[r], g[r][11]);
                g[r][12] = fmaf(wd.x, hk[r], g[r][12]);
                g[r][13] = fmaf(wd.y, hk[r], g[r][13]);
                g[r][14] = fmaf(wd.z, hk[r], g[r][14]);
                g[r][15] = fmaf(wd.w, hk[r], g[r][15]);
            }
        }
        __syncthreads();   // all reads of sH for layer l complete

        // relu + writeback: 16 b64 (2 packed rows per channel).
#pragma unroll
        for (int jj = 0; jj < 16; jj++) {
            float2 hv;
            hv.x = fmaxf(g[0][jj], 0.f);
            hv.y = fmaxf(g[1][jj], 0.f);
            *(float2*)(sH + (jo + jj) * RB + lane * 2) = hv;
        }
        __syncthreads();   // h ready for next layer / output
    }

    // Output layer collapsed over mi: v[:,mj] = C[:,mj] + C[:,mj+2]
    float v0[RPL], v1[RPL];
    const float b02 = bout[0] + bout[2], b13 = bout[1] + bout[3];
#pragma unroll
    for (int r = 0; r < RPL; r++) { v0[r] = b02; v1[r] = b13; }
#pragma unroll 8
    for (int k = 0; k < 64; k++) {
        const float4 wo = ((const float4*)Wout)[k];     // s_load
        const float wxz = wo.x + wo.z, wyw = wo.y + wo.w;
        const float2 hv = *(const float2*)(sH + k * RB + lane * 2);
        v0[0] = fmaf(hv.x, wxz, v0[0]);  v1[0] = fmaf(hv.x, wyw, v1[0]);
        v0[1] = fmaf(hv.y, wxz, v0[1]);  v1[1] = fmaf(hv.y, wyw, v1[1]);
    }

    // Fused scatter, deduplicated: all 4 waves hold identical v0/v1 for the
    // same rows (output sum is over all 64 k, wave-independent). Wave 0
    // scatters r=0, wave 1 scatters r=1, waves 2-3 skip -> each of the
    // block's 128 rows lands exactly once. Static selects (no dynamic
    // register indexing -> no scratch).
    if (wave < 2) {
        const int mrow = mb0 + wave;
        if (mrow < MM) {
            const float sv0 = wave == 0 ? v0[0] : v0[1];
            const float sv1 = wave == 0 ? v1[0] : v1[1];
            const int r2 = coo[mrow] * 2;        // row index * MODES
            const int c2 = coo[MM + mrow] * 2;   // col index * MODES
            const long long f0i = (long long)r2 * DD + c2;
            unsafeAtomicAdd(out + f0i, sv0);            // (2i, 2j)
            unsafeAtomicAdd(out + f0i + DD + 1, sv1);   // (2i+1, 2j+1)
        }
    }
}

extern "C" void kernel_launch(void* const* d_in, const int* in_sizes, int n_in,
                              void* d_out, int out_size, void* d_ws, size_t ws_size,
                              hipStream_t stream) {
    const float* CK   = (const float*)d_in[0];
    const float* Win  = (const float*)d_in[1];
    const float* bin  = (const float*)d_in[2];
    const float* Whid = (const float*)d_in[3];
    const float* bhid = (const float*)d_in[4];
    const float* Wout = (const float*)d_in[5];
    const float* bout = (const float*)d_in[6];
    const int* coo    = (const int*)d_in[7];
    float* out        = (float*)d_out;

    // Zero the 576MB output on the rocclr fill path (proven 6.15 TB/s on
    // this buffer); stream-ordered ahead of the fused MLP+scatter.
    hipMemsetAsync(out, 0, OUTBYTES, stream);
    mlp_scatter<<<MLPGRID, BLK, 0, stream>>>(
        CK, Win, bin, Whid, bhid, Wout, bout, coo, out);
}